// Round 17
// baseline (508.963 us; speedup 1.0000x reference)
//
#include <hip/hip_runtime.h>
#include <hip/hip_bf16.h>

#define E_EDGES   250000
#define D_NODE    128
#define D_EMB     200
#define D_STATIC  64
#define F_DIM     520
#define NT        33        // n-tiles of 16 (528 cols; tile 32 = cols 512..527, pack-zeroed past 519)
#define KT        17        // k-steps of 32 (544 k padded; cols 528..543 zero)
#define RS        552       // LDS row stride bf16. MUST stay 16B-aligned (R9/R10: 564 = 8 mod 16
                            // -> odd-row ds_read_b128 misaligned -> 2x LDS time). 552 = 1104B,
                            // 276 dw mod 32 = 20, gcd 4 -> 2 lanes/bank = free (m136). Optimal.
#define BM        64        // edges per tile
#define NBLK      3907      // ceil(E/BM)
#define GRID      256       // persistent blocks, 1/CU
#define PANEL     (BM * RS * 2)      // 70656 B
#define SMEM_BYTES (2 * PANEL)       // 141312 B double panel -> 1 block/CU

typedef __attribute__((ext_vector_type(8))) short frag_t;   // 8 bf16 = 4 VGPR
typedef __attribute__((ext_vector_type(4))) float f32x4;

// Packed f32->bf16 (RTNE), 1 inst per pair (R15: +4% vs scalar twiddle).
__device__ __forceinline__ unsigned int cvtpk(float lo, float hi) {
    unsigned int r;
    asm("v_cvt_pk_bf16_f32 %0, %1, %2" : "=v"(r) : "v"(lo), "v"(hi));
    return r;
}
__device__ __forceinline__ unsigned short f2bf(float x) {   // cold paths (pack kernels)
    union { float f; unsigned int u; } v; v.f = x;
    unsigned int r = v.u + 0x7FFFu + ((v.u >> 16) & 1u);
    return (unsigned short)(r >> 16);
}
__device__ __forceinline__ float bf2f(unsigned short u) {
    union { float f; unsigned int i; } v; v.i = ((unsigned int)u) << 16; return v.f;
}
__device__ __forceinline__ float elu(float z) {
    return (z > 0.0f) ? z : (__expf(z) - 1.0f);
}

__global__ void pack_w_kernel(const float* __restrict__ W, unsigned short* __restrict__ Wp,
                              int ntiles, int krows, int ncols, int ldw) {
    int t = blockIdx.x * blockDim.x + threadIdx.x;
    if (t >= ntiles * KT * 64) return;
    int nt   = t / (KT * 64);
    int rem  = t % (KT * 64);
    int kt   = rem / 64;
    int lane = rem % 64;
    int n  = nt * 16 + (lane & 15);
    int kb = kt * 32 + (lane >> 4) * 8;
    unsigned short v[8];
    #pragma unroll
    for (int j = 0; j < 8; ++j) {
        int k = kb + j;
        float w = (k < krows && n < ncols) ? W[(long long)k * ldw + n] : 0.0f;
        v[j] = f2bf(w);
    }
    unsigned short* dst = Wp + (long long)t * 8;
    #pragma unroll
    for (int j = 0; j < 8; ++j) dst[j] = v[j];
}

// Zero-padded bias (544 f32): epilogue reads float4 unguarded; pad cols get
// bias 0 -> elu(0)+h(0) = 0 stays exactly 0 (tile 32 needs no special case).
__global__ void pack_bias_kernel(const float* __restrict__ b, float* __restrict__ bp) {
    int i = blockIdx.x * blockDim.x + threadIdx.x;
    if (i < 544) bp[i] = (i < F_DIM) ? b[i] : 0.0f;
}

// ---------------- gather pieces (one gather wave = 16 rows) ----------------
__device__ __forceinline__ int gather_idx(const int* __restrict__ eidx,
                                          long long nbase, int g, int lane) {
    int myidx = 0;
    if (lane < 32) {
        long long e = nbase + g * 16 + (lane & 15);
        if (e >= E_EDGES) e = E_EDGES - 1;                  // clamp: junk rows never stored
        myidx = eidx[(long long)(lane >> 4) * E_EDGES + e];
    }
    return myidx;
}
__device__ __forceinline__ void gather_X(char* __restrict__ hp, const float* __restrict__ X,
                                         int myidx, int g, int lane) {
    #pragma unroll 1
    for (int gg = 0; gg < 4; ++gg) {
        #pragma unroll
        for (int rr = 0; rr < 4; ++rr) {
            const int r = g * 16 + gg * 4 + rr;
            char* row = hp + (size_t)r * (RS * 2);
            const int src = __shfl(myidx, gg * 4 + rr);
            const int dst = __shfl(myidx, 16 + gg * 4 + rr);
            float2 v = *(const float2*)(X + (long long)src * D_NODE + lane * 2);
            *(unsigned int*)(row + lane * 4) = cvtpk(v.x, v.y);
            float2 w = *(const float2*)(X + (long long)dst * D_NODE + lane * 2);
            *(unsigned int*)(row + 256 + lane * 4) = cvtpk(w.x, w.y);
        }
    }
}
__device__ __forceinline__ void gather_sef(char* __restrict__ hp, const float* __restrict__ sef,
                                           long long nbase, int g, int lane) {
    #pragma unroll 1
    for (int q = 0; q < 4; ++q) {
        const int r = g * 16 + q * 4 + (lane >> 4);
        long long e = nbase + r;
        if (e >= E_EDGES) e = E_EDGES - 1;
        char* row = hp + (size_t)r * (RS * 2);
        float4 v = *(const float4*)(sef + e * D_STATIC + (long long)(lane & 15) * 4);
        *(uint2*)(row + 912 + (lane & 15) * 8) = make_uint2(cvtpk(v.x, v.y), cvtpk(v.z, v.w));
        if ((lane & 15) < 6)   // zero pad cols 520..543
            *(uint2*)(row + 1040 + (lane & 15) * 8) = make_uint2(0u, 0u);
    }
}
__device__ __forceinline__ void gather_emb(char* __restrict__ hp, const float* __restrict__ emb,
                                           long long nbase, int g, int lane) {
    #pragma unroll 1
    for (int gg = 0; gg < 4; ++gg) {
        #pragma unroll
        for (int rr = 0; rr < 4; ++rr) {
            if (lane < 50) {
                const int r = g * 16 + gg * 4 + rr;
                long long e = nbase + r;
                if (e >= E_EDGES) e = E_EDGES - 1;
                char* row = hp + (size_t)r * (RS * 2);
                float4 v = *(const float4*)(emb + e * D_EMB + (long long)lane * 4);
                *(uint2*)(row + 512 + lane * 8) = make_uint2(cvtpk(v.x, v.y), cvtpk(v.z, v.w));
            }
        }
    }
}

// ---------------- compute pieces ----------------
// K-loop: acc[CNT][4] over 64 rows; ROLLED (R4-R6 spill) + depth-1 B ping-pong
// (R12: single-buffer serializes MFMA vs ~200cy L2 waits; at acc=48 the
// ping-pong finally fits the 128-reg/wave cap).
template<int CNT>
__device__ __forceinline__ void kacc(const char* __restrict__ hc,
                                     const unsigned short* __restrict__ Wp,
                                     int nt0, int lane, f32x4 (&acc)[CNT][4]) {
    const int idx = lane & 15;
    const int grp = lane >> 4;
    const char* wb = (const char*)Wp + (size_t)lane * 16;
    const char* abase = hc + (size_t)idx * (RS * 2) + grp * 16;

    #pragma unroll
    for (int t = 0; t < CNT; ++t)
        #pragma unroll
        for (int m = 0; m < 4; ++m)
            acc[t][m] = (f32x4){0.f, 0.f, 0.f, 0.f};

    auto loadB = [&](frag_t* dst, int kt) {
        #pragma unroll
        for (int t = 0; t < CNT; ++t)
            dst[t] = *(const frag_t*)(wb + (size_t)((nt0 + t) * KT + kt) * 1024);
    };
    auto step = [&](const frag_t* b, int kt) {
        {   // chunk 0: m = 0..1
            frag_t a[2];
            #pragma unroll
            for (int m = 0; m < 2; ++m)
                a[m] = *(const frag_t*)(abase + (size_t)(m * 16) * (RS * 2) + kt * 64);
            #pragma unroll
            for (int t = 0; t < CNT; ++t)
                #pragma unroll
                for (int m = 0; m < 2; ++m)
                    acc[t][m] = __builtin_amdgcn_mfma_f32_16x16x32_bf16(b[t], a[m], acc[t][m], 0, 0, 0);
        }
        {   // chunk 1: m = 2..3
            frag_t a[2];
            #pragma unroll
            for (int m = 0; m < 2; ++m)
                a[m] = *(const frag_t*)(abase + (size_t)((m + 2) * 16) * (RS * 2) + kt * 64);
            #pragma unroll
            for (int t = 0; t < CNT; ++t)
                #pragma unroll
                for (int m = 0; m < 2; ++m)
                    acc[t][m + 2] = __builtin_amdgcn_mfma_f32_16x16x32_bf16(b[t], a[m], acc[t][m + 2], 0, 0, 0);
        }
    };

    frag_t bA[CNT], bB[CNT];
    loadB(bA, 0);
    #pragma unroll 1
    for (int kp = 0; kp < 8; ++kp) {
        loadB(bB, 2 * kp + 1);
        step(bA, 2 * kp);
        loadB(bA, 2 * kp + 2);
        step(bB, 2 * kp + 1);
    }
    step(bA, 16);
}

template<int CNT>
__device__ __forceinline__ void epi(char* __restrict__ hc, const float* __restrict__ biasp,
                                    int nt0, int lane, f32x4 (&acc)[CNT][4]) {
    const int idx = lane & 15;
    const int grp = lane >> 4;
    #pragma unroll
    for (int t = 0; t < CNT; ++t) {
        const int colb = (nt0 + t) * 16 + grp * 4;          // <= 524; biasp zero-padded
        const float4 bb = *(const float4*)(biasp + colb);
        #pragma unroll
        for (int m = 0; m < 4; ++m) {
            const int row = m * 16 + idx;
            char* p = hc + (size_t)row * (RS * 2) + (size_t)colb * 2;
            ushort4 hv = *(const ushort4*)p;
            float z0 = elu(acc[t][m][0] + bb.x) + bf2f(hv.x);
            float z1 = elu(acc[t][m][1] + bb.y) + bf2f(hv.y);
            float z2 = elu(acc[t][m][2] + bb.z) + bf2f(hv.z);
            float z3 = elu(acc[t][m][3] + bb.w) + bf2f(hv.w);
            *(uint2*)p = make_uint2(cvtpk(z0, z1), cvtpk(z2, z3));
        }
    }
}

// Full compute iteration for one tile: 5 barriers (matched by gather path).
template<int CNT>
__device__ __forceinline__ void compute_iter(char* __restrict__ hc,
                                             const unsigned short* __restrict__ W1p,
                                             const unsigned short* __restrict__ W2p,
                                             const unsigned short* __restrict__ Woutp,
                                             const float* __restrict__ b1p,
                                             const float* __restrict__ b2p,
                                             const float* __restrict__ bout,
                                             float* __restrict__ out,
                                             int nt0, int wave, int lane, long long base) {
    f32x4 acc[CNT][4];
    kacc<CNT>(hc, W1p, nt0, lane, acc);
    __syncthreads();                                   // B1: layer1 A-reads done
    epi<CNT>(hc, b1p, nt0, lane, acc);
    __syncthreads();                                   // B2: layer1 written
    kacc<CNT>(hc, W2p, nt0, lane, acc);
    __syncthreads();                                   // B3: layer2 A-reads done
    epi<CNT>(hc, b2p, nt0, lane, acc);
    __syncthreads();                                   // B4: layer2 written
    if (wave < 4) {                                    // out-proj: rows 16w..16w+15
        const int idx = lane & 15;
        const int grp = lane >> 4;
        f32x4 a4 = (f32x4){0.f, 0.f, 0.f, 0.f};
        #pragma unroll 1
        for (int kt = 0; kt < KT; ++kt) {
            frag_t b = *(const frag_t*)((const char*)Woutp + (size_t)kt * 1024 + (size_t)lane * 16);
            frag_t a = *(const frag_t*)(hc + (size_t)(wave * 16 + idx) * (RS * 2) + kt * 64 + grp * 16);
            a4 = __builtin_amdgcn_mfma_f32_16x16x32_bf16(b, a, a4, 0, 0, 0);
        }
        if (grp < 2) {
            const long long e = base + wave * 16 + idx;
            if (e < E_EDGES) {
                float4 bb = *(const float4*)(bout + grp * 4);
                *(float4*)(out + e * 8 + grp * 4) =
                    make_float4(a4[0] + bb.x, a4[1] + bb.y, a4[2] + bb.z, a4[3] + bb.w);
            }
        }
    }
    __syncthreads();                                   // B0: tile done, panel free
}

__global__ __launch_bounds__(1024, 4)
void edge_mlp_kernel(const float* __restrict__ X, const int* __restrict__ eidx,
                     const float* __restrict__ emb, const float* __restrict__ sef,
                     const float* __restrict__ bout,
                     const float* __restrict__ b1p, const float* __restrict__ b2p,
                     const unsigned short* __restrict__ W1p,
                     const unsigned short* __restrict__ W2p,
                     const unsigned short* __restrict__ Woutp,
                     float* __restrict__ out) {
    extern __shared__ char smem[];
    // NOTE: no pointer ARRAY over LDS (R16 compile error: addrspacecast in
    // static initializer). Panel pointers computed arithmetically each use.
    const int tid  = threadIdx.x;
    const int wave = tid >> 6;           // 0..11 compute, 12..15 gather
    const int lane = tid & 63;

    // prologue: gather waves fill panel 0 with this block's first tile
    if (wave >= 12) {
        const int g = wave - 12;
        const long long nbase = (long long)blockIdx.x * BM;
        int mi = gather_idx(eidx, nbase, g, lane);
        gather_X(smem, X, mi, g, lane);
        gather_sef(smem, sef, nbase, g, lane);
        gather_emb(smem, emb, nbase, g, lane);
    }
    __syncthreads();

    int cur = 0;
    #pragma unroll 1
    for (int t = blockIdx.x; t < NBLK; t += GRID) {
        char* hc = smem + (size_t)cur * PANEL;
        char* hn = smem + (size_t)(cur ^ 1) * PANEL;
        const long long base = (long long)t * BM;
        const bool hasNext = (t + GRID < NBLK);
        const long long nbase = (long long)(t + GRID) * BM;

        if (wave < 9) {
            compute_iter<3>(hc, W1p, W2p, Woutp, b1p, b2p, bout, out,
                            wave * 3, wave, lane, base);
        } else if (wave < 12) {
            compute_iter<2>(hc, W1p, W2p, Woutp, b1p, b2p, bout, out,
                            27 + (wave - 9) * 2, wave, lane, base);
        } else {
            // producer path: fill panel[nxt] for tile t+GRID, chunks spread
            // across the same 5 barriers the compute path executes.
            const int g = wave - 12;
            int mi = 0;
            if (hasNext) {
                mi = gather_idx(eidx, nbase, g, lane);
                gather_X(hn, X, mi, g, lane);
            }
            __syncthreads();                           // B1
            if (hasNext) gather_sef(hn, sef, nbase, g, lane);
            __syncthreads();                           // B2
            if (hasNext) gather_emb(hn, emb, nbase, g, lane);
            __syncthreads();                           // B3
            __syncthreads();                           // B4
            __syncthreads();                           // B0
        }
        cur ^= 1;
    }
}

extern "C" void kernel_launch(void* const* d_in, const int* in_sizes, int n_in,
                              void* d_out, int out_size, void* d_ws, size_t ws_size,
                              hipStream_t stream) {
    const float* X    = (const float*)d_in[0];
    const int*   eidx = (const int*)d_in[1];
    const float* emb  = (const float*)d_in[2];
    const float* sef  = (const float*)d_in[3];
    const float* W1   = (const float*)d_in[4];
    const float* b1   = (const float*)d_in[5];
    const float* W2   = (const float*)d_in[6];
    const float* b2   = (const float*)d_in[7];
    const float* Wout = (const float*)d_in[8];
    const float* bout = (const float*)d_in[9];
    float* out = (float*)d_out;

    unsigned short* W1p   = (unsigned short*)d_ws;                 // 33*17*512 bf16
    unsigned short* W2p   = W1p + (size_t)NT * KT * 512;
    unsigned short* Woutp = W2p + (size_t)NT * KT * 512;           // 17*512 bf16
    float* b1p = (float*)(Woutp + (size_t)KT * 512);               // 544 f32 each
    float* b2p = b1p + 544;

    int total = NT * KT * 64;
    pack_w_kernel<<<(total + 255) / 256, 256, 0, stream>>>(W1, W1p, NT, F_DIM, F_DIM, F_DIM);
    pack_w_kernel<<<(total + 255) / 256, 256, 0, stream>>>(W2, W2p, NT, F_DIM, F_DIM, F_DIM);
    pack_w_kernel<<<(KT * 64 + 255) / 256, 256, 0, stream>>>(Wout, Woutp, 1, F_DIM, 8, 8);
    pack_bias_kernel<<<3, 256, 0, stream>>>(b1, b1p);
    pack_bias_kernel<<<3, 256, 0, stream>>>(b2, b2p);

    (void)hipFuncSetAttribute((const void*)edge_mlp_kernel,
                              hipFuncAttributeMaxDynamicSharedMemorySize, SMEM_BYTES);
    edge_mlp_kernel<<<GRID, 1024, SMEM_BYTES, stream>>>(
        X, eidx, emb, sef, bout, b1p, b2p, W1p, W2p, Woutp, out);
}

// Round 18
// 408.038 us; speedup vs baseline: 1.2473x; 1.2473x over previous
//
#include <hip/hip_runtime.h>
#include <hip/hip_bf16.h>

#define E_EDGES   250000
#define D_NODE    128
#define D_EMB     200
#define D_STATIC  64
#define F_DIM     520
#define CT32      16        // 32-wide col-tiles (cols 0..511)
#define KT32      34        // k-steps of 16 (544 k padded)
#define KT        17        // k-steps of 32 (old 16x16 path: rem tile + out-proj)
#define RS        552       // LDS row stride bf16. MUST stay 16B-aligned (R9/R10: 564 = 8 mod 16
                            // -> odd-row ds_read_b128 misaligned -> 2x LDS time). For 32-row
                            // reads at 552: each bank gets exactly 8 accesses/instr = the 1KB
                            // floor -> conflict-free. 16-row reads: 2 lanes/bank = free (m136).
#define BM        64        // edges per block -> 2 independent blocks/CU (R11/R13/R17:
                            // single-block lockstep loses ~10-30%)
#define SMEM_BYTES (BM * RS * 2)   // 70656 B

typedef __attribute__((ext_vector_type(8)))  short frag_t;   // 8 bf16 = 4 VGPR
typedef __attribute__((ext_vector_type(4)))  float f32x4;
typedef __attribute__((ext_vector_type(16))) float f32x16;

// Packed f32->bf16 (RTNE), 1 inst per pair (R15: +4% vs scalar twiddle).
__device__ __forceinline__ unsigned int cvtpk(float lo, float hi) {
    unsigned int r;
    asm("v_cvt_pk_bf16_f32 %0, %1, %2" : "=v"(r) : "v"(lo), "v"(hi));
    return r;
}
__device__ __forceinline__ unsigned short f2bf(float x) {   // cold paths (pack kernels)
    union { float f; unsigned int u; } v; v.f = x;
    unsigned int r = v.u + 0x7FFFu + ((v.u >> 16) & 1u);
    return (unsigned short)(r >> 16);
}
__device__ __forceinline__ float bf2f(unsigned short u) {
    union { float f; unsigned int i; } v; v.i = ((unsigned int)u) << 16; return v.f;
}
__device__ __forceinline__ float elu(float z) {
    return (z > 0.0f) ? z : (__expf(z) - 1.0f);
}

// 32-wide operand pack for mfma_f32_32x32x16_bf16:
// Wq[((ct*KT32 + kt)*64 + lane)*8 + j] = W[kt*16 + (lane>>5)*8 + j][ct*32 + (lane&31)]
// (same lane/k-group convention as the verified 16-wide pack; k zero-padded past F_DIM).
__global__ void pack_w32_kernel(const float* __restrict__ W, unsigned short* __restrict__ Wq,
                                int ldw) {
    int t = blockIdx.x * blockDim.x + threadIdx.x;
    if (t >= CT32 * KT32 * 64) return;
    int ct   = t / (KT32 * 64);
    int rem  = t % (KT32 * 64);
    int kt   = rem / 64;
    int lane = rem % 64;
    int n  = ct * 32 + (lane & 31);            // < 512, always a real column
    int kb = kt * 16 + (lane >> 5) * 8;
    unsigned short v[8];
    #pragma unroll
    for (int j = 0; j < 8; ++j) {
        int k = kb + j;
        v[j] = (k < F_DIM) ? f2bf(W[(long long)k * ldw + n]) : (unsigned short)0;
    }
    unsigned short* dst = Wq + (long long)t * 8;
    #pragma unroll
    for (int j = 0; j < 8; ++j) dst[j] = v[j];
}

// 16-wide pack (old layout) for rem tile (cols 512..527) and Wout.
__global__ void pack_w_kernel(const float* __restrict__ W, unsigned short* __restrict__ Wp,
                              int ntiles, int krows, int ncols, int ldw) {
    int t = blockIdx.x * blockDim.x + threadIdx.x;
    if (t >= ntiles * KT * 64) return;
    int nt   = t / (KT * 64);
    int rem  = t % (KT * 64);
    int kt   = rem / 64;
    int lane = rem % 64;
    int n  = nt * 16 + (lane & 15);
    int kb = kt * 32 + (lane >> 4) * 8;
    unsigned short v[8];
    #pragma unroll
    for (int j = 0; j < 8; ++j) {
        int k = kb + j;
        float w = (k < krows && n < ncols) ? W[(long long)k * ldw + n] : 0.0f;
        v[j] = f2bf(w);
    }
    unsigned short* dst = Wp + (long long)t * 8;
    #pragma unroll
    for (int j = 0; j < 8; ++j) dst[j] = v[j];
}

// Zero-padded bias (544 f32): unguarded float4 reads; pad cols get bias 0 so
// elu(0)+h(0)=0 keeps pad columns exactly 0.
__global__ void pack_bias_kernel(const float* __restrict__ b, float* __restrict__ bp) {
    int i = blockIdx.x * blockDim.x + threadIdx.x;
    if (i < 544) bp[i] = (i < F_DIM) ? b[i] : 0.0f;
}

// One residual-MLP layer, in place on the 64x552 bf16 LDS panel.
// Main path 32x32x16: wave w owns col-tiles {2w, 2w+1} (cols 64w..64w+63),
// both 32-row halves -> acc[2][2] f32x16 = 64 regs, only 2 B-frags live/kt.
// This is what finally fits ping-pong + 2 blocks/CU + 4 waves/SIMD (R14's
// spill was acc68 + 4 B-frags). Waves 0..3 also run the 16-wide rem tile
// (cols 512..527, rows 16w..16w+15) on the proven 16x16x32 path every other kt.
// K-loop ROLLED (R4-R6: unrolled bodies spill ~500MB).
__device__ __forceinline__ void layer_pass(char* __restrict__ h,
                                           const unsigned short* __restrict__ Wq,
                                           const unsigned short* __restrict__ Wr,
                                           const float* __restrict__ biasp,
                                           int wave, int lane) {
    const int l31 = lane & 31;
    const int hi  = lane >> 5;
    const int idx = lane & 15;
    const int grp = lane >> 4;
    const int ct0 = wave * 2;
    const bool t32 = (wave < 4);
    const char* wb  = (const char*)Wq + (size_t)lane * 16;
    const char* wbr = (const char*)Wr + (size_t)lane * 16;
    const char* abase   = h + (size_t)l31 * (RS * 2) + hi * 16;            // + rt*32 rows
    const char* a32base = h + (size_t)(wave * 16 + idx) * (RS * 2) + grp * 16;

    f32x16 acc00 = {0}, acc01 = {0}, acc10 = {0}, acc11 = {0};
    f32x4  accr  = (f32x4){0.f, 0.f, 0.f, 0.f};

    auto loadB = [&](frag_t* d, int kt) {
        d[0] = *(const frag_t*)(wb + (size_t)((ct0 + 0) * KT32 + kt) * 1024);
        d[1] = *(const frag_t*)(wb + (size_t)((ct0 + 1) * KT32 + kt) * 1024);
    };
    auto step = [&](const frag_t* b, int kt) {
        frag_t a0 = *(const frag_t*)(abase + kt * 32);
        frag_t a1 = *(const frag_t*)(abase + (size_t)32 * (RS * 2) + kt * 32);
        if (t32 && (kt & 1) == 0) {                 // rem tile: one k32-step per kt-pair
            frag_t b32 = *(const frag_t*)(wbr + (size_t)(kt >> 1) * 1024);
            frag_t a32 = *(const frag_t*)(a32base + (kt >> 1) * 64);
            accr = __builtin_amdgcn_mfma_f32_16x16x32_bf16(b32, a32, accr, 0, 0, 0);
        }
        acc00 = __builtin_amdgcn_mfma_f32_32x32x16_bf16(b[0], a0, acc00, 0, 0, 0);
        acc01 = __builtin_amdgcn_mfma_f32_32x32x16_bf16(b[0], a1, acc01, 0, 0, 0);
        acc10 = __builtin_amdgcn_mfma_f32_32x32x16_bf16(b[1], a0, acc10, 0, 0, 0);
        acc11 = __builtin_amdgcn_mfma_f32_32x32x16_bf16(b[1], a1, acc11, 0, 0, 0);
    };

    frag_t bA[2], bB[2];
    loadB(bA, 0);
    #pragma unroll 1
    for (int kp = 0; kp < 17; ++kp) {               // 34 k16-steps, depth-1 ping-pong
        loadB(bB, 2 * kp + 1);
        step(bA, 2 * kp);
        if (kp < 16) loadB(bA, 2 * kp + 2);
        step(bB, 2 * kp + 1);
    }

    __syncthreads();   // all A-reads done -> safe to overwrite h in place

    // epilogue 32x32 tiles: C/D map col=lane&31(edge row), M=(reg&3)+8*(reg>>2)+4*hi.
    // Per lane: 4 groups of 4 consecutive n -> uint2 writes, as before.
    #pragma unroll
    for (int ct = 0; ct < 2; ++ct) {
        #pragma unroll
        for (int rt = 0; rt < 2; ++rt) {
            const f32x16 a = (ct == 0) ? (rt == 0 ? acc00 : acc01)
                                       : (rt == 0 ? acc10 : acc11);
            const int row = rt * 32 + l31;
            char* prow = h + (size_t)row * (RS * 2);
            #pragma unroll
            for (int g = 0; g < 4; ++g) {
                const int n0 = (ct0 + ct) * 32 + g * 8 + hi * 4;   // < 512+..: real cols
                const float4 bb = *(const float4*)(biasp + n0);
                char* p = prow + (size_t)n0 * 2;
                ushort4 hv = *(const ushort4*)p;
                float z0 = elu(a[g * 4 + 0] + bb.x) + bf2f(hv.x);
                float z1 = elu(a[g * 4 + 1] + bb.y) + bf2f(hv.y);
                float z2 = elu(a[g * 4 + 2] + bb.z) + bf2f(hv.z);
                float z3 = elu(a[g * 4 + 3] + bb.w) + bf2f(hv.w);
                *(uint2*)p = make_uint2(cvtpk(z0, z1), cvtpk(z2, z3));
            }
        }
    }
    if (t32) {   // rem tile: cols 512..527, rows 16w..16w+15; biasp pad keeps 520+ at 0
        const int colb = 512 + grp * 4;
        const float4 bb = *(const float4*)(biasp + colb);
        const int row = wave * 16 + idx;
        char* p = h + (size_t)row * (RS * 2) + (size_t)colb * 2;
        ushort4 hv = *(const ushort4*)p;
        float z0 = elu(accr[0] + bb.x) + bf2f(hv.x);
        float z1 = elu(accr[1] + bb.y) + bf2f(hv.y);
        float z2 = elu(accr[2] + bb.z) + bf2f(hv.z);
        float z3 = elu(accr[3] + bb.w) + bf2f(hv.w);
        *(uint2*)p = make_uint2(cvtpk(z0, z1), cvtpk(z2, z3));
    }
    __syncthreads();
}

__global__ __launch_bounds__(512, 4)
void edge_mlp_kernel(const float* __restrict__ X, const int* __restrict__ eidx,
                     const float* __restrict__ emb, const float* __restrict__ sef,
                     const float* __restrict__ bout,
                     const float* __restrict__ b1p, const float* __restrict__ b2p,
                     const unsigned short* __restrict__ W1q,
                     const unsigned short* __restrict__ W2q,
                     const unsigned short* __restrict__ W1r,
                     const unsigned short* __restrict__ W2r,
                     const unsigned short* __restrict__ Woutp,
                     float* __restrict__ out) {
    extern __shared__ char h[];          // 64 x 552 bf16, in-place panel
    const int tid  = threadIdx.x;
    const int wave = tid >> 6;           // 0..7
    const int lane = tid & 63;
    const long long base = (long long)blockIdx.x * BM;

    // ---- gather + f32->bf16 into h, wave w owns rows 8w..8w+7 (R15 code) ----
    int myidx = 0;
    if (lane < 16) {
        long long e = base + wave * 8 + (lane & 7);
        if (e >= E_EDGES) e = E_EDGES - 1;           // clamp: junk rows never stored
        myidx = eidx[(long long)(lane >> 3) * E_EDGES + e];
    }

    #pragma unroll 1
    for (int g = 0; g < 2; ++g) {
        #pragma unroll
        for (int rr = 0; rr < 4; ++rr) {
            const int r = wave * 8 + g * 4 + rr;
            char* row = h + (size_t)r * (RS * 2);
            const int src = __shfl(myidx, g * 4 + rr);
            const int dst = __shfl(myidx, 8 + g * 4 + rr);
            float2 v = *(const float2*)(X + (long long)src * D_NODE + lane * 2);
            *(unsigned int*)(row + lane * 4) = cvtpk(v.x, v.y);
            float2 w = *(const float2*)(X + (long long)dst * D_NODE + lane * 2);
            *(unsigned int*)(row + 256 + lane * 4) = cvtpk(w.x, w.y);
        }
    }
    #pragma unroll 1
    for (int g = 0; g < 2; ++g) {
        #pragma unroll
        for (int rr = 0; rr < 4; ++rr) {
            if (lane < 50) {   // 200 emb floats per row
                long long e = base + wave * 8 + g * 4 + rr;
                if (e >= E_EDGES) e = E_EDGES - 1;
                char* row = h + (size_t)(wave * 8 + g * 4 + rr) * (RS * 2);
                float4 v = *(const float4*)(emb + e * D_EMB + (long long)lane * 4);
                *(uint2*)(row + 512 + lane * 8) = make_uint2(cvtpk(v.x, v.y), cvtpk(v.z, v.w));
            }
        }
    }
    #pragma unroll 1
    for (int q = 0; q < 2; ++q) {      // static: 4 rows per iteration (64 floats/row)
        const int r = wave * 8 + q * 4 + (lane >> 4);
        long long e = base + r;
        if (e >= E_EDGES) e = E_EDGES - 1;
        char* row = h + (size_t)r * (RS * 2);
        float4 v = *(const float4*)(sef + e * D_STATIC + (long long)(lane & 15) * 4);
        *(uint2*)(row + 912 + (lane & 15) * 8) = make_uint2(cvtpk(v.x, v.y), cvtpk(v.z, v.w));
        if ((lane & 15) < 6)          // zero pad cols 520..543 (48 B per row)
            *(uint2*)(row + 1040 + (lane & 15) * 8) = make_uint2(0u, 0u);
    }
    __syncthreads();

    layer_pass(h, W1q, W1r, b1p, wave, lane);   // h = elu(h@W1+b1)+h
    layer_pass(h, W2q, W2r, b2p, wave, lane);   // h = elu(h@W2+b2)+h

    // ---- output projection: waves 0..3, wave w owns rows 16w..16w+15 (16x16 path) ----
    if (wave < 4) {
        const int idx = lane & 15;
        const int grp = lane >> 4;
        f32x4 acc = (f32x4){0.f, 0.f, 0.f, 0.f};
        #pragma unroll 1
        for (int kt = 0; kt < KT; ++kt) {
            frag_t b = *(const frag_t*)((const char*)Woutp + (size_t)kt * 1024 + (size_t)lane * 16);
            frag_t a = *(const frag_t*)(h + (size_t)(wave * 16 + idx) * (RS * 2) + kt * 64 + grp * 16);
            acc = __builtin_amdgcn_mfma_f32_16x16x32_bf16(b, a, acc, 0, 0, 0);
        }
        if (grp < 2) {   // cols 0..7 real, grp>=2 are n-pad
            const long long e = base + wave * 16 + idx;
            if (e < E_EDGES) {
                float4 bb = *(const float4*)(bout + grp * 4);
                *(float4*)(out + e * 8 + grp * 4) =
                    make_float4(acc[0] + bb.x, acc[1] + bb.y, acc[2] + bb.z, acc[3] + bb.w);
            }
        }
    }
}

extern "C" void kernel_launch(void* const* d_in, const int* in_sizes, int n_in,
                              void* d_out, int out_size, void* d_ws, size_t ws_size,
                              hipStream_t stream) {
    const float* X    = (const float*)d_in[0];
    const int*   eidx = (const int*)d_in[1];
    const float* emb  = (const float*)d_in[2];
    const float* sef  = (const float*)d_in[3];
    const float* W1   = (const float*)d_in[4];
    const float* b1   = (const float*)d_in[5];
    const float* W2   = (const float*)d_in[6];
    const float* b2   = (const float*)d_in[7];
    const float* Wout = (const float*)d_in[8];
    const float* bout = (const float*)d_in[9];
    float* out = (float*)d_out;

    const size_t W32SZ = (size_t)CT32 * KT32 * 512;   // 278528 bf16
    const size_t W16SZ = (size_t)KT * 512;            // 8704 bf16
    unsigned short* W1q   = (unsigned short*)d_ws;
    unsigned short* W2q   = W1q + W32SZ;
    unsigned short* W1r   = W2q + W32SZ;
    unsigned short* W2r   = W1r + W16SZ;
    unsigned short* Woutp = W2r + W16SZ;
    float* b1p = (float*)(Woutp + W16SZ);
    float* b2p = b1p + 544;

    int t32tot = CT32 * KT32 * 64;
    pack_w32_kernel<<<(t32tot + 255) / 256, 256, 0, stream>>>(W1, W1q, F_DIM);
    pack_w32_kernel<<<(t32tot + 255) / 256, 256, 0, stream>>>(W2, W2q, F_DIM);
    pack_w_kernel<<<(KT * 64 + 255) / 256, 256, 0, stream>>>(W1 + 512, W1r, 1, F_DIM, 8, F_DIM);
    pack_w_kernel<<<(KT * 64 + 255) / 256, 256, 0, stream>>>(W2 + 512, W2r, 1, F_DIM, 8, F_DIM);
    pack_w_kernel<<<(KT * 64 + 255) / 256, 256, 0, stream>>>(Wout, Woutp, 1, F_DIM, 8, 8);
    pack_bias_kernel<<<3, 256, 0, stream>>>(b1, b1p);
    pack_bias_kernel<<<3, 256, 0, stream>>>(b2, b2p);

    (void)hipFuncSetAttribute((const void*)edge_mlp_kernel,
                              hipFuncAttributeMaxDynamicSharedMemorySize, SMEM_BYTES);
    int nblocks = (E_EDGES + BM - 1) / BM;
    edge_mlp_kernel<<<nblocks, 512, SMEM_BYTES, stream>>>(
        X, eidx, emb, sef, bout, b1p, b2p, W1q, W2q, W1r, W2r, Woutp, out);
}

// Round 19
// 361.739 us; speedup vs baseline: 1.4070x; 1.1280x over previous
//
#include <hip/hip_runtime.h>
#include <hip/hip_bf16.h>

#define E_EDGES   250000
#define D_NODE    128
#define D_EMB     200
#define D_STATIC  64
#define F_DIM     520
#define NT        33        // n-tiles of 16 (528 real cols; tile 32 = cols 512..527)
#define KT        17        // k-steps of 32 (544 k padded; cols 528..543 zero)
#define RS        552       // LDS row stride bf16. MUST stay 16B-aligned (R9/R10:
                            // RS=564 = 8 mod 16 made odd-row ds_read_b128 misaligned
                            // -> 2x LDS time, -90%). 552 = 1104B, 276 dw mod 32 = 20,
                            // gcd 4 -> uniform 2 lanes/bank = free (m136). Optimal.
#define BM        64        // edges (rows) per block
#define SMEM_BYTES (BM * RS * 2)   // 70656 B -> 2 independent blocks/CU
                            // (R11/R13/R17: 1-block lockstep loses 10-30%;
                            //  R14: ping-pong spills at this budget; R18: 32x32
                            //  MFMA loses ILP -> this geometry is the optimum)

typedef __attribute__((ext_vector_type(8))) short frag_t;   // 8 bf16 = 4 VGPR
typedef __attribute__((ext_vector_type(4))) float f32x4;

// Packed f32->bf16 (RTNE), 1 inst per pair (R15: +4% vs scalar twiddle).
__device__ __forceinline__ unsigned int cvtpk(float lo, float hi) {
    unsigned int r;
    asm("v_cvt_pk_bf16_f32 %0, %1, %2" : "=v"(r) : "v"(lo), "v"(hi));
    return r;
}
__device__ __forceinline__ unsigned short f2bf(float x) {   // cold paths (pack kernels)
    union { float f; unsigned int u; } v; v.f = x;
    unsigned int r = v.u + 0x7FFFu + ((v.u >> 16) & 1u);
    return (unsigned short)(r >> 16);
}
__device__ __forceinline__ float bf2f(unsigned short u) {
    union { float f; unsigned int i; } v; v.i = ((unsigned int)u) << 16; return v.f;
}
__device__ __forceinline__ float elu(float z) {
    return (z > 0.0f) ? z : (__expf(z) - 1.0f);
}

// Pack W[k][n] (f32, row-major, ldw) into fragment-ordered bf16:
// Wp[((nt*KT + kt)*64 + lane)*8 + j] = W[kt*32 + (lane>>4)*8 + j][nt*16 + (lane&15)]
// zero outside (krows, ncols).
__global__ void pack_w_kernel(const float* __restrict__ W, unsigned short* __restrict__ Wp,
                              int ntiles, int krows, int ncols, int ldw) {
    int t = blockIdx.x * blockDim.x + threadIdx.x;
    if (t >= ntiles * KT * 64) return;
    int nt   = t / (KT * 64);
    int rem  = t % (KT * 64);
    int kt   = rem / 64;
    int lane = rem % 64;
    int n  = nt * 16 + (lane & 15);
    int kb = kt * 32 + (lane >> 4) * 8;
    unsigned short v[8];
    #pragma unroll
    for (int j = 0; j < 8; ++j) {
        int k = kb + j;
        float w = (k < krows && n < ncols) ? W[(long long)k * ldw + n] : 0.0f;
        v[j] = f2bf(w);
    }
    unsigned short* dst = Wp + (long long)t * 8;
    #pragma unroll
    for (int j = 0; j < 8; ++j) dst[j] = v[j];
}

// One residual-MLP layer, in place on the 64x552 bf16 LDS panel.
// 8 waves: wave w owns ntiles 4w..4w+3 over all 64 rows (acc[4][4]=64 regs);
// waves 0..3 also fold tile 32 (cols 512..527), rows 16w..16w+15.
// Single-buffered B (R14: ping-pong spills here), A chunked 2-at-a-time,
// K-loop ROLLED (R4-R6: unrolled bodies spill ~500MB).
// R19: WAVE-STAGGERED kt order. Accumulation is kt-order-independent; rotating
// each wave's start by (wave&3)*4 decorrelates the per-kt B-load bursts and
// MFMA phases across the 4 resident waves/SIMD, so one wave's MFMAs issue
// under another's ~200cy L2 wait (R15 diagnosis: all pipes <=40%, waves
// stalled in lockstep on the same load window).
__device__ __forceinline__ void layer_pass(char* __restrict__ h,
                                           const unsigned short* __restrict__ Wp,
                                           const float* __restrict__ bias,
                                           int wave, int lane) {
    const int idx = lane & 15;
    const int grp = lane >> 4;
    const int nt0 = wave * 4;
    const bool t32 = (wave < 4);
    const int kst = (wave & 3) * 4;     // stagger offset
    const char* wb = (const char*)Wp + (size_t)lane * 16;
    const char* abase   = h + (size_t)idx * (RS * 2) + grp * 16;
    const char* a32base = h + (size_t)(wave * 16 + idx) * (RS * 2) + grp * 16;

    f32x4 acc[4][4];
    #pragma unroll
    for (int t = 0; t < 4; ++t)
        #pragma unroll
        for (int m = 0; m < 4; ++m)
            acc[t][m] = (f32x4){0.f, 0.f, 0.f, 0.f};
    f32x4 acc32 = (f32x4){0.f, 0.f, 0.f, 0.f};

    #pragma unroll 1
    for (int kti = 0; kti < KT; ++kti) {
        int kt = kti + kst; if (kt >= KT) kt -= KT;   // rotated kt sequence
        frag_t b[4];
        #pragma unroll
        for (int t = 0; t < 4; ++t)
            b[t] = *(const frag_t*)(wb + (size_t)((nt0 + t) * KT + kt) * 1024);
        frag_t b32, a32;
        if (t32) {
            b32 = *(const frag_t*)(wb + (size_t)(32 * KT + kt) * 1024);
            a32 = *(const frag_t*)(a32base + kt * 64);
        }
        {   // chunk 0: m = 0..1 (live A = 8 regs)
            frag_t a[2];
            #pragma unroll
            for (int m = 0; m < 2; ++m)
                a[m] = *(const frag_t*)(abase + (size_t)(m * 16) * (RS * 2) + kt * 64);
            #pragma unroll
            for (int t = 0; t < 4; ++t)
                #pragma unroll
                for (int m = 0; m < 2; ++m)
                    acc[t][m] = __builtin_amdgcn_mfma_f32_16x16x32_bf16(b[t], a[m], acc[t][m], 0, 0, 0);
        }
        {   // chunk 1: m = 2..3
            frag_t a[2];
            #pragma unroll
            for (int m = 0; m < 2; ++m)
                a[m] = *(const frag_t*)(abase + (size_t)((m + 2) * 16) * (RS * 2) + kt * 64);
            #pragma unroll
            for (int t = 0; t < 4; ++t)
                #pragma unroll
                for (int m = 0; m < 2; ++m)
                    acc[t][m + 2] = __builtin_amdgcn_mfma_f32_16x16x32_bf16(b[t], a[m], acc[t][m + 2], 0, 0, 0);
        }
        if (t32)
            acc32 = __builtin_amdgcn_mfma_f32_16x16x32_bf16(b32, a32, acc32, 0, 0, 0);
    }

    __syncthreads();   // all A-reads done -> safe to overwrite h in place

    // epilogue: h = elu(z + b) + h; conversions via packed cvt (2 insts per 4 vals)
    #pragma unroll
    for (int t = 0; t < 4; ++t) {
        const int colb = (nt0 + t) * 16 + grp * 4;          // <= 496+12 < 520
        const float4 bb = *(const float4*)(bias + colb);
        #pragma unroll
        for (int m = 0; m < 4; ++m) {
            const int row = m * 16 + idx;
            char* p = h + (size_t)row * (RS * 2) + (size_t)colb * 2;
            ushort4 hv = *(const ushort4*)p;
            float z0 = elu(acc[t][m][0] + bb.x) + bf2f(hv.x);
            float z1 = elu(acc[t][m][1] + bb.y) + bf2f(hv.y);
            float z2 = elu(acc[t][m][2] + bb.z) + bf2f(hv.z);
            float z3 = elu(acc[t][m][3] + bb.w) + bf2f(hv.w);
            *(uint2*)p = make_uint2(cvtpk(z0, z1), cvtpk(z2, z3));
        }
    }
    if (t32) {   // cols 512..527, rows 16*wave..+15 (bias 0 past col 519)
        const int colb = 512 + grp * 4;
        float bb[4];
        #pragma unroll
        for (int q = 0; q < 4; ++q) bb[q] = (colb + q < F_DIM) ? bias[colb + q] : 0.0f;
        const int row = wave * 16 + idx;
        char* p = h + (size_t)row * (RS * 2) + (size_t)colb * 2;
        ushort4 hv = *(const ushort4*)p;
        float z0 = elu(acc32[0] + bb[0]) + bf2f(hv.x);
        float z1 = elu(acc32[1] + bb[1]) + bf2f(hv.y);
        float z2 = elu(acc32[2] + bb[2]) + bf2f(hv.z);
        float z3 = elu(acc32[3] + bb[3]) + bf2f(hv.w);
        *(uint2*)p = make_uint2(cvtpk(z0, z1), cvtpk(z2, z3));
    }
    __syncthreads();
}

__global__ __launch_bounds__(512, 4)
void edge_mlp_kernel(const float* __restrict__ X, const int* __restrict__ eidx,
                     const float* __restrict__ emb, const float* __restrict__ sef,
                     const float* __restrict__ b1, const float* __restrict__ b2,
                     const float* __restrict__ bout,
                     const unsigned short* __restrict__ W1p,
                     const unsigned short* __restrict__ W2p,
                     const unsigned short* __restrict__ Woutp,
                     float* __restrict__ out) {
    extern __shared__ char h[];          // 64 x 552 bf16, in-place panel
    const int tid  = threadIdx.x;
    const int wave = tid >> 6;           // 0..7
    const int lane = tid & 63;
    const long long base = (long long)blockIdx.x * BM;

    // ---- gather + f32->bf16 into h, wave w owns rows 8w..8w+7 ----
    // Lanes 0..15 fetch the wave's 16 indices (8 src + 8 dst); __shfl distributes.
    // Out-of-range edges CLAMPED (junk rows never stored -> harmless).
    // Outer loops rolled: 4 rows in flight caps VGPR pressure (R4-R6 spill lesson).
    int myidx = 0;
    if (lane < 16) {
        long long e = base + wave * 8 + (lane & 7);
        if (e >= E_EDGES) e = E_EDGES - 1;
        myidx = eidx[(long long)(lane >> 3) * E_EDGES + e];
    }

    #pragma unroll 1
    for (int g = 0; g < 2; ++g) {
        #pragma unroll
        for (int rr = 0; rr < 4; ++rr) {
            const int r = wave * 8 + g * 4 + rr;
            char* row = h + (size_t)r * (RS * 2);
            const int src = __shfl(myidx, g * 4 + rr);
            const int dst = __shfl(myidx, 8 + g * 4 + rr);
            float2 v = *(const float2*)(X + (long long)src * D_NODE + lane * 2);
            *(unsigned int*)(row + lane * 4) = cvtpk(v.x, v.y);
            float2 w = *(const float2*)(X + (long long)dst * D_NODE + lane * 2);
            *(unsigned int*)(row + 256 + lane * 4) = cvtpk(w.x, w.y);
        }
    }
    #pragma unroll 1
    for (int g = 0; g < 2; ++g) {
        #pragma unroll
        for (int rr = 0; rr < 4; ++rr) {
            if (lane < 50) {   // 200 emb floats per row
                long long e = base + wave * 8 + g * 4 + rr;
                if (e >= E_EDGES) e = E_EDGES - 1;
                char* row = h + (size_t)(wave * 8 + g * 4 + rr) * (RS * 2);
                float4 v = *(const float4*)(emb + e * D_EMB + (long long)lane * 4);
                *(uint2*)(row + 512 + lane * 8) =
                    make_uint2(cvtpk(v.x, v.y), cvtpk(v.z, v.w));
            }
        }
    }
    #pragma unroll 1
    for (int q = 0; q < 2; ++q) {      // static: 4 rows per iteration (64 floats/row)
        const int r = wave * 8 + q * 4 + (lane >> 4);
        long long e = base + r;
        if (e >= E_EDGES) e = E_EDGES - 1;
        char* row = h + (size_t)r * (RS * 2);
        float4 v = *(const float4*)(sef + e * D_STATIC + (long long)(lane & 15) * 4);
        *(uint2*)(row + 912 + (lane & 15) * 8) =
            make_uint2(cvtpk(v.x, v.y), cvtpk(v.z, v.w));
        if ((lane & 15) < 6)          // zero pad cols 520..543 (48 B per row)
            *(uint2*)(row + 1040 + (lane & 15) * 8) = make_uint2(0u, 0u);
    }
    __syncthreads();

    layer_pass(h, W1p, b1, wave, lane);   // h = elu(h@W1+b1)+h
    layer_pass(h, W2p, b2, wave, lane);   // h = elu(h@W2+b2)+h

    // ---- output projection: waves 0..3, wave w owns rows 16w..16w+15 ----
    if (wave < 4) {
        const int idx = lane & 15;
        const int grp = lane >> 4;
        f32x4 acc = (f32x4){0.f, 0.f, 0.f, 0.f};
        #pragma unroll 1
        for (int kt = 0; kt < KT; ++kt) {
            frag_t b = *(const frag_t*)((const char*)Woutp + (size_t)kt * 1024 + (size_t)lane * 16);
            frag_t a = *(const frag_t*)(h + (size_t)(wave * 16 + idx) * (RS * 2) + kt * 64 + grp * 16);
            acc = __builtin_amdgcn_mfma_f32_16x16x32_bf16(b, a, acc, 0, 0, 0);
        }
        if (grp < 2) {   // cols 0..7 real, grp>=2 are n-pad
            const long long e = base + wave * 16 + idx;
            if (e < E_EDGES) {
                float4 bb = *(const float4*)(bout + grp * 4);
                float4 o = make_float4(acc[0] + bb.x, acc[1] + bb.y,
                                       acc[2] + bb.z, acc[3] + bb.w);
                *(float4*)(out + e * 8 + grp * 4) = o;
            }
        }
    }
}

extern "C" void kernel_launch(void* const* d_in, const int* in_sizes, int n_in,
                              void* d_out, int out_size, void* d_ws, size_t ws_size,
                              hipStream_t stream) {
    const float* X    = (const float*)d_in[0];
    const int*   eidx = (const int*)d_in[1];
    const float* emb  = (const float*)d_in[2];
    const float* sef  = (const float*)d_in[3];
    const float* W1   = (const float*)d_in[4];
    const float* b1   = (const float*)d_in[5];
    const float* W2   = (const float*)d_in[6];
    const float* b2   = (const float*)d_in[7];
    const float* Wout = (const float*)d_in[8];
    const float* bout = (const float*)d_in[9];
    float* out = (float*)d_out;

    unsigned short* W1p   = (unsigned short*)d_ws;                 // 33*17*512 bf16
    unsigned short* W2p   = W1p + (size_t)NT * KT * 512;
    unsigned short* Woutp = W2p + (size_t)NT * KT * 512;           // 17*512 bf16

    int total = NT * KT * 64;
    pack_w_kernel<<<(total + 255) / 256, 256, 0, stream>>>(W1, W1p, NT, F_DIM, F_DIM, F_DIM);
    pack_w_kernel<<<(total + 255) / 256, 256, 0, stream>>>(W2, W2p, NT, F_DIM, F_DIM, F_DIM);
    pack_w_kernel<<<(KT * 64 + 255) / 256, 256, 0, stream>>>(Wout, Woutp, 1, F_DIM, 8, 8);

    (void)hipFuncSetAttribute((const void*)edge_mlp_kernel,
                              hipFuncAttributeMaxDynamicSharedMemorySize, SMEM_BYTES);
    int nblocks = (E_EDGES + BM - 1) / BM;
    edge_mlp_kernel<<<nblocks, 512, SMEM_BYTES, stream>>>(
        X, eidx, emb, sef, b1, b2, bout, W1p, W2p, Woutp, out);
}

// Round 20
// 346.302 us; speedup vs baseline: 1.4697x; 1.0446x over previous
//
#include <hip/hip_runtime.h>
#include <hip/hip_bf16.h>

#define E_EDGES   250000
#define D_NODE    128
#define D_EMB     200
#define D_STATIC  64
#define F_DIM     520
#define NT        33        // n-tiles of 16 (528 real cols; tile 32 = cols 512..527)
#define KT        17        // k-steps of 32 (544 k padded; cols 528..543 zero)
#define RS        552       // LDS row stride bf16. MUST stay 16B-aligned (R9/R10:
                            // RS=564 = 8 mod 16 made odd-row ds_read_b128 misaligned
                            // -> 2x LDS time, -90%). 552 = 1104B, 276 dw mod 32 = 20,
                            // gcd 4 -> uniform 2 lanes/bank = free (m136). Optimal.
#define BM        64        // edges (rows) per block
#define SMEM_BYTES (BM * RS * 2)   // 70656 B -> 2 independent blocks/CU
                            // (R11/R13/R17: 1-block lockstep loses 10-30%;
                            //  R14: ping-pong spills at this budget; R18: 32x32
                            //  MFMA loses ILP; R19: kt-stagger neutral-negative.
                            //  This geometry is the measured optimum.)

typedef __attribute__((ext_vector_type(8))) short frag_t;   // 8 bf16 = 4 VGPR
typedef __attribute__((ext_vector_type(4))) float f32x4;

// Packed f32->bf16 (RTNE), 1 inst per pair (R15: +4% vs scalar twiddle).
__device__ __forceinline__ unsigned int cvtpk(float lo, float hi) {
    unsigned int r;
    asm("v_cvt_pk_bf16_f32 %0, %1, %2" : "=v"(r) : "v"(lo), "v"(hi));
    return r;
}
__device__ __forceinline__ unsigned short f2bf(float x) {   // cold paths (pack kernels)
    union { float f; unsigned int u; } v; v.f = x;
    unsigned int r = v.u + 0x7FFFu + ((v.u >> 16) & 1u);
    return (unsigned short)(r >> 16);
}
__device__ __forceinline__ float bf2f(unsigned short u) {
    union { float f; unsigned int i; } v; v.i = ((unsigned int)u) << 16; return v.f;
}
__device__ __forceinline__ float elu(float z) {
    return (z > 0.0f) ? z : (__expf(z) - 1.0f);
}

// Pack W[k][n] (f32, row-major, ldw) into fragment-ordered bf16:
// Wp[((nt*KT + kt)*64 + lane)*8 + j] = W[kt*32 + (lane>>4)*8 + j][nt*16 + (lane&15)]
// zero outside (krows, ncols).
__global__ void pack_w_kernel(const float* __restrict__ W, unsigned short* __restrict__ Wp,
                              int ntiles, int krows, int ncols, int ldw) {
    int t = blockIdx.x * blockDim.x + threadIdx.x;
    if (t >= ntiles * KT * 64) return;
    int nt   = t / (KT * 64);
    int rem  = t % (KT * 64);
    int kt   = rem / 64;
    int lane = rem % 64;
    int n  = nt * 16 + (lane & 15);
    int kb = kt * 32 + (lane >> 4) * 8;
    unsigned short v[8];
    #pragma unroll
    for (int j = 0; j < 8; ++j) {
        int k = kb + j;
        float w = (k < krows && n < ncols) ? W[(long long)k * ldw + n] : 0.0f;
        v[j] = f2bf(w);
    }
    unsigned short* dst = Wp + (long long)t * 8;
    #pragma unroll
    for (int j = 0; j < 8; ++j) dst[j] = v[j];
}

// One residual-MLP layer, in place on the 64x552 bf16 LDS panel.
// 8 waves: wave w owns ntiles 4w..4w+3 over all 64 rows (acc[4][4]=64 regs);
// waves 0..3 also fold tile 32 (cols 512..527), rows 16w..16w+15.
// Single-buffered B (R14: ping-pong spills here), A chunked 2-at-a-time,
// K-loop ROLLED (R4-R6: unrolled bodies spill ~500MB).
// R20: s_setprio(1) around each kt's MFMA cluster (T5). Our 2 independent
// blocks/CU put co-resident waves at different phases (one block gathering/
// epiloguing while the other K-loops) -- the setprio-favorable regime (attn
// +4-7%), unlike barrier-lockstep GEMM where it's null.
__device__ __forceinline__ void layer_pass(char* __restrict__ h,
                                           const unsigned short* __restrict__ Wp,
                                           const float* __restrict__ bias,
                                           int wave, int lane) {
    const int idx = lane & 15;
    const int grp = lane >> 4;
    const int nt0 = wave * 4;
    const bool t32 = (wave < 4);
    const char* wb = (const char*)Wp + (size_t)lane * 16;
    const char* abase   = h + (size_t)idx * (RS * 2) + grp * 16;
    const char* a32base = h + (size_t)(wave * 16 + idx) * (RS * 2) + grp * 16;

    f32x4 acc[4][4];
    #pragma unroll
    for (int t = 0; t < 4; ++t)
        #pragma unroll
        for (int m = 0; m < 4; ++m)
            acc[t][m] = (f32x4){0.f, 0.f, 0.f, 0.f};
    f32x4 acc32 = (f32x4){0.f, 0.f, 0.f, 0.f};

    #pragma unroll 1
    for (int kt = 0; kt < KT; ++kt) {
        frag_t b[4];
        #pragma unroll
        for (int t = 0; t < 4; ++t)
            b[t] = *(const frag_t*)(wb + (size_t)((nt0 + t) * KT + kt) * 1024);
        frag_t b32, a32;
        if (t32) {
            b32 = *(const frag_t*)(wb + (size_t)(32 * KT + kt) * 1024);
            a32 = *(const frag_t*)(a32base + kt * 64);
        }
        __builtin_amdgcn_s_setprio(1);
        {   // chunk 0: m = 0..1 (live A = 8 regs)
            frag_t a[2];
            #pragma unroll
            for (int m = 0; m < 2; ++m)
                a[m] = *(const frag_t*)(abase + (size_t)(m * 16) * (RS * 2) + kt * 64);
            #pragma unroll
            for (int t = 0; t < 4; ++t)
                #pragma unroll
                for (int m = 0; m < 2; ++m)
                    acc[t][m] = __builtin_amdgcn_mfma_f32_16x16x32_bf16(b[t], a[m], acc[t][m], 0, 0, 0);
        }
        {   // chunk 1: m = 2..3
            frag_t a[2];
            #pragma unroll
            for (int m = 0; m < 2; ++m)
                a[m] = *(const frag_t*)(abase + (size_t)((m + 2) * 16) * (RS * 2) + kt * 64);
            #pragma unroll
            for (int t = 0; t < 4; ++t)
                #pragma unroll
                for (int m = 0; m < 2; ++m)
                    acc[t][m + 2] = __builtin_amdgcn_mfma_f32_16x16x32_bf16(b[t], a[m], acc[t][m + 2], 0, 0, 0);
        }
        if (t32)
            acc32 = __builtin_amdgcn_mfma_f32_16x16x32_bf16(b32, a32, acc32, 0, 0, 0);
        __builtin_amdgcn_s_setprio(0);
    }

    __syncthreads();   // all A-reads done -> safe to overwrite h in place

    // epilogue: h = elu(z + b) + h; conversions via packed cvt (2 insts per 4 vals)
    #pragma unroll
    for (int t = 0; t < 4; ++t) {
        const int colb = (nt0 + t) * 16 + grp * 4;          // <= 496+12 < 520
        const float4 bb = *(const float4*)(bias + colb);
        #pragma unroll
        for (int m = 0; m < 4; ++m) {
            const int row = m * 16 + idx;
            char* p = h + (size_t)row * (RS * 2) + (size_t)colb * 2;
            ushort4 hv = *(const ushort4*)p;
            float z0 = elu(acc[t][m][0] + bb.x) + bf2f(hv.x);
            float z1 = elu(acc[t][m][1] + bb.y) + bf2f(hv.y);
            float z2 = elu(acc[t][m][2] + bb.z) + bf2f(hv.z);
            float z3 = elu(acc[t][m][3] + bb.w) + bf2f(hv.w);
            *(uint2*)p = make_uint2(cvtpk(z0, z1), cvtpk(z2, z3));
        }
    }
    if (t32) {   // cols 512..527, rows 16*wave..+15 (bias 0 past col 519)
        const int colb = 512 + grp * 4;
        float bb[4];
        #pragma unroll
        for (int q = 0; q < 4; ++q) bb[q] = (colb + q < F_DIM) ? bias[colb + q] : 0.0f;
        const int row = wave * 16 + idx;
        char* p = h + (size_t)row * (RS * 2) + (size_t)colb * 2;
        ushort4 hv = *(const ushort4*)p;
        float z0 = elu(acc32[0] + bb[0]) + bf2f(hv.x);
        float z1 = elu(acc32[1] + bb[1]) + bf2f(hv.y);
        float z2 = elu(acc32[2] + bb[2]) + bf2f(hv.z);
        float z3 = elu(acc32[3] + bb[3]) + bf2f(hv.w);
        *(uint2*)p = make_uint2(cvtpk(z0, z1), cvtpk(z2, z3));
    }
    __syncthreads();
}

__global__ __launch_bounds__(512, 4)
void edge_mlp_kernel(const float* __restrict__ X, const int* __restrict__ eidx,
                     const float* __restrict__ emb, const float* __restrict__ sef,
                     const float* __restrict__ b1, const float* __restrict__ b2,
                     const float* __restrict__ bout,
                     const unsigned short* __restrict__ W1p,
                     const unsigned short* __restrict__ W2p,
                     const unsigned short* __restrict__ Woutp,
                     float* __restrict__ out) {
    extern __shared__ char h[];          // 64 x 552 bf16, in-place panel
    const int tid  = threadIdx.x;
    const int wave = tid >> 6;           // 0..7
    const int lane = tid & 63;
    const long long base = (long long)blockIdx.x * BM;

    // ---- gather + f32->bf16 into h, wave w owns rows 8w..8w+7 ----
    // Lanes 0..15 fetch the wave's 16 indices (8 src + 8 dst); __shfl distributes.
    // Out-of-range edges CLAMPED (junk rows never stored -> harmless).
    // Outer loops rolled: 4 rows in flight caps VGPR pressure (R4-R6 spill lesson).
    int myidx = 0;
    if (lane < 16) {
        long long e = base + wave * 8 + (lane & 7);
        if (e >= E_EDGES) e = E_EDGES - 1;
        myidx = eidx[(long long)(lane >> 3) * E_EDGES + e];
    }

    #pragma unroll 1
    for (int g = 0; g < 2; ++g) {
        #pragma unroll
        for (int rr = 0; rr < 4; ++rr) {
            const int r = wave * 8 + g * 4 + rr;
            char* row = h + (size_t)r * (RS * 2);
            const int src = __shfl(myidx, g * 4 + rr);
            const int dst = __shfl(myidx, 8 + g * 4 + rr);
            float2 v = *(const float2*)(X + (long long)src * D_NODE + lane * 2);
            *(unsigned int*)(row + lane * 4) = cvtpk(v.x, v.y);
            float2 w = *(const float2*)(X + (long long)dst * D_NODE + lane * 2);
            *(unsigned int*)(row + 256 + lane * 4) = cvtpk(w.x, w.y);
        }
    }
    #pragma unroll 1
    for (int g = 0; g < 2; ++g) {
        #pragma unroll
        for (int rr = 0; rr < 4; ++rr) {
            if (lane < 50) {   // 200 emb floats per row
                long long e = base + wave * 8 + g * 4 + rr;
                if (e >= E_EDGES) e = E_EDGES - 1;
                char* row = h + (size_t)(wave * 8 + g * 4 + rr) * (RS * 2);
                float4 v = *(const float4*)(emb + e * D_EMB + (long long)lane * 4);
                *(uint2*)(row + 512 + lane * 8) =
                    make_uint2(cvtpk(v.x, v.y), cvtpk(v.z, v.w));
            }
        }
    }
    #pragma unroll 1
    for (int q = 0; q < 2; ++q) {      // static: 4 rows per iteration (64 floats/row)
        const int r = wave * 8 + q * 4 + (lane >> 4);
        long long e = base + r;
        if (e >= E_EDGES) e = E_EDGES - 1;
        char* row = h + (size_t)r * (RS * 2);
        float4 v = *(const float4*)(sef + e * D_STATIC + (long long)(lane & 15) * 4);
        *(uint2*)(row + 912 + (lane & 15) * 8) =
            make_uint2(cvtpk(v.x, v.y), cvtpk(v.z, v.w));
        if ((lane & 15) < 6)          // zero pad cols 520..543 (48 B per row)
            *(uint2*)(row + 1040 + (lane & 15) * 8) = make_uint2(0u, 0u);
    }
    __syncthreads();

    layer_pass(h, W1p, b1, wave, lane);   // h = elu(h@W1+b1)+h
    layer_pass(h, W2p, b2, wave, lane);   // h = elu(h@W2+b2)+h

    // ---- output projection: waves 0..3, wave w owns rows 16w..16w+15 ----
    if (wave < 4) {
        const int idx = lane & 15;
        const int grp = lane >> 4;
        f32x4 acc = (f32x4){0.f, 0.f, 0.f, 0.f};
        #pragma unroll 1
        for (int kt = 0; kt < KT; ++kt) {
            frag_t b = *(const frag_t*)((const char*)Woutp + (size_t)kt * 1024 + (size_t)lane * 16);
            frag_t a = *(const frag_t*)(h + (size_t)(wave * 16 + idx) * (RS * 2) + kt * 64 + grp * 16);
            acc = __builtin_amdgcn_mfma_f32_16x16x32_bf16(b, a, acc, 0, 0, 0);
        }
        if (grp < 2) {   // cols 0..7 real, grp>=2 are n-pad
            const long long e = base + wave * 16 + idx;
            if (e < E_EDGES) {
                float4 bb = *(const float4*)(bout + grp * 4);
                float4 o = make_float4(acc[0] + bb.x, acc[1] + bb.y,
                                       acc[2] + bb.z, acc[3] + bb.w);
                *(float4*)(out + e * 8 + grp * 4) = o;
            }
        }
    }
}

extern "C" void kernel_launch(void* const* d_in, const int* in_sizes, int n_in,
                              void* d_out, int out_size, void* d_ws, size_t ws_size,
                              hipStream_t stream) {
    const float* X    = (const float*)d_in[0];
    const int*   eidx = (const int*)d_in[1];
    const float* emb  = (const float*)d_in[2];
    const float* sef  = (const float*)d_in[3];
    const float* W1   = (const float*)d_in[4];
    const float* b1   = (const float*)d_in[5];
    const float* W2   = (const float*)d_in[6];
    const float* b2   = (const float*)d_in[7];
    const float* Wout = (const float*)d_in[8];
    const float* bout = (const float*)d_in[9];
    float* out = (float*)d_out;

    unsigned short* W1p   = (unsigned short*)d_ws;                 // 33*17*512 bf16
    unsigned short* W2p   = W1p + (size_t)NT * KT * 512;
    unsigned short* Woutp = W2p + (size_t)NT * KT * 512;           // 17*512 bf16

    int total = NT * KT * 64;
    pack_w_kernel<<<(total + 255) / 256, 256, 0, stream>>>(W1, W1p, NT, F_DIM, F_DIM, F_DIM);
    pack_w_kernel<<<(total + 255) / 256, 256, 0, stream>>>(W2, W2p, NT, F_DIM, F_DIM, F_DIM);
    pack_w_kernel<<<(KT * 64 + 255) / 256, 256, 0, stream>>>(Wout, Woutp, 1, F_DIM, 8, 8);

    (void)hipFuncSetAttribute((const void*)edge_mlp_kernel,
                              hipFuncAttributeMaxDynamicSharedMemorySize, SMEM_BYTES);
    int nblocks = (E_EDGES + BM - 1) / BM;
    edge_mlp_kernel<<<nblocks, 512, SMEM_BYTES, stream>>>(
        X, eidx, emb, sef, b1, b2, bout, W1p, W2p, Woutp, out);
}